// Round 2
// baseline (103514.648 us; speedup 1.0000x reference)
//
#include <hip/hip_runtime.h>

#define NF 8

typedef float f2 __attribute__((ext_vector_type(2)));
typedef float f4 __attribute__((ext_vector_type(4)));

#define WAIT_GE(IDX, LIM)                                              \
  while (__hip_atomic_load(&cnt[IDX], __ATOMIC_ACQUIRE,                \
                           __HIP_MEMORY_SCOPE_WORKGROUP) < (LIM)) {}

// R9: single-wave recurrences. 4 waves = 256 threads, 1 wave/SIMD.
//  wave0 (A): entire L0 cell (64 units, 4 gate rows/lane). h0 recurrence is
//             wave-internal (in-order DS): no sync on the critical cycle.
//  wave1 (B): entire L1 cell; W_ih1@h0 comes precomputed (per-gate 32-col
//             slice partials) from helpers, so B's path is only W_hh1@h1.
//  wave2 (H1): W_ih1 gates 0,1 partials; xproj gates 0,1 (lead 5); hid.
//  wave3 (H2): W_ih1 gates 2,3 partials; xproj gates 2,3; out+obuf+stores.
//  Each helper keeps a private tbuf copy (no H1<->H2 coupling on IO).
// All dot products replicate the validated quad-split FP order exactly
// (slice rotations, f2 lo/hi accumulation, combine trees, exp chains).
// Counters: cnt[0]=A steps, cnt[1]=B steps, cnt[2]=partial releases
// (2/step), cnt[4]/cnt[5] = H1/H2 full-step counters (b64-polled by A).
__global__ __launch_bounds__(256, 1) void decoder_p9(
    const float* __restrict__ h0in, const float* __restrict__ c0in,
    const float* __restrict__ diffp, const float* __restrict__ target,
    const float* __restrict__ Wih0, const float* __restrict__ Whh0,
    const float* __restrict__ bih0, const float* __restrict__ bhh0,
    const float* __restrict__ Wih1, const float* __restrict__ Whh1,
    const float* __restrict__ bih1, const float* __restrict__ bhh1,
    const float* __restrict__ Whid, const float* __restrict__ bhidp,
    const float* __restrict__ Woutp, const float* __restrict__ boutp,
    float* __restrict__ outp, const int T)
{
  const int tid = threadIdx.x;
  const int wv  = tid >> 6;
  const int u   = tid & 63;

  __shared__ alignas(256) float h0r[8][64];
  __shared__ alignas(256) float h1r[4][64];
  __shared__ alignas(256) float xprojS[8][4][64];
  __shared__ alignas(256) float partS[8][4][2][64];
  __shared__ alignas(256) float hidS[8][32];
  __shared__ alignas(256) float obuf[64 * NF];
  __shared__ alignas(256) float tbufA[2][32 * NF];
  __shared__ alignas(256) float tbufB[2][32 * NF];
  __shared__ alignas(32) int cnt[8];

  // ---- per-role register state (paths are disjoint; dead arrays cost 0) ----
  f2 wA[4][4][4][2];
  f2 wB[4][2][8][2];
  f2 wi[2][2][8][2];
  f2 xw[2][4];
  float xd[2];
  f2 wh[4][4][2];
  float bh = 0.f;
  f2 wo[4][2][2];
  float bo = 0.f;
  float b4[4];
  float cS = 0.f, hS = 0.f;

  const int hx = (wv >= 2) ? (wv - 2) : 0;   // helper index
  const int gb = 2 * hx;                     // helper gate base
  float (*tb)[32 * NF] = hx ? tbufB : tbufA;

  // ================= INIT =================
  if (wv == 0) {
    #pragma unroll
    for (int g = 0; g < 4; ++g)
      #pragma unroll
      for (int m = 0; m < 4; ++m)
        #pragma unroll
        for (int c = 0; c < 4; ++c) {
          const int ch = (c + m) & 3;
          const f4 v = *(const f4*)(Whh0 + (64 * g + u) * 64 + 16 * m + 4 * ch);
          wA[g][m][c][0] = v.lo;
          wA[g][m][c][1] = v.hi;
        }
    #pragma unroll
    for (int g = 0; g < 4; ++g) b4[g] = bih0[64 * g + u] + bhh0[64 * g + u];
    cS = c0in[u];
    h0r[7][u] = h0in[u];
    #pragma unroll
    for (int g = 0; g < 4; ++g) xprojS[0][g][u] = 0.f;
    if (tid == 0) {
      #pragma unroll
      for (int i = 0; i < 8; ++i) cnt[i] = 0;
    }
  } else if (wv == 1) {
    #pragma unroll
    for (int g = 0; g < 4; ++g)
      #pragma unroll
      for (int ls = 0; ls < 2; ++ls)
        #pragma unroll
        for (int c = 0; c < 8; ++c) {
          const int ch = (c + 4 + 2 * ls) & 7;
          const f4 v = *(const f4*)(Whh1 + (64 * g + u) * 64 + 32 * ls + 4 * ch);
          wB[g][ls][c][0] = v.lo;
          wB[g][ls][c][1] = v.hi;
        }
    #pragma unroll
    for (int g = 0; g < 4; ++g) b4[g] = bih1[64 * g + u] + bhh1[64 * g + u];
    cS = c0in[64 + u];
    h1r[3][u] = h0in[64 + u];
  } else {
    #pragma unroll
    for (int gl = 0; gl < 2; ++gl)
      #pragma unroll
      for (int ls = 0; ls < 2; ++ls)
        #pragma unroll
        for (int c = 0; c < 8; ++c) {
          const int ch = (c + 2 * ls) & 7;
          const f4 v =
              *(const f4*)(Wih1 + (64 * (gb + gl) + u) * 64 + 32 * ls + 4 * ch);
          wi[gl][ls][c][0] = v.lo;
          wi[gl][ls][c][1] = v.hi;
        }
    #pragma unroll
    for (int gl = 0; gl < 2; ++gl) {
      const float* ra = Wih0 + (64 * (gb + gl) + u) * 14;
      #pragma unroll
      for (int c = 0; c < 4; ++c) xw[gl][c] = (f2){ra[2 * c], ra[2 * c + 1]};
      float x = 0.f;
      #pragma unroll
      for (int m = 0; m < 6; ++m) x += ra[8 + m] * diffp[m];
      xd[gl] = x;
    }
    if (hx == 0 && u < 32) {
      #pragma unroll
      for (int m = 0; m < 4; ++m)
        #pragma unroll
        for (int c = 0; c < 4; ++c) {
          const int ch = (c + m) & 3;
          const f4 v = *(const f4*)(Whid + u * 64 + 16 * m + 4 * ch);
          wh[m][c][0] = v.lo;
          wh[m][c][1] = v.hi;
        }
      bh = bhidp[u];
    }
    if (hx == 1 && u < 8) {
      #pragma unroll
      for (int k2 = 0; k2 < 4; ++k2)
        #pragma unroll
        for (int c = 0; c < 2; ++c) {
          const int ch = (c + k2) & 1;
          const f4 v = *(const f4*)(Woutp + u * 32 + 8 * k2 + 4 * ch);
          wo[k2][c][0] = v.lo;
          wo[k2][c][1] = v.hi;
        }
      bo = boutp[u];
    }
    if (u < T) {  // seed rows 0..63 (both buffers) of own tbuf copy
      *(f4*)&((float*)tb)[u * 8]     = *(const f4*)&target[u * 8];
      *(f4*)&((float*)tb)[u * 8 + 4] = *(const f4*)&target[u * 8 + 4];
    }
  }
  __syncthreads();

  // xproj seeds t=1..4 (in-loop production starts at t=5)
  if (wv >= 2) {
    #pragma unroll
    for (int tt = 1; tt <= 4; ++tt) {
      if (tt <= T - 1) {
        const f4* trow = (const f4*)&tb[0][(tt - 1) * NF];
        const f4 r0 = trow[0], r1 = trow[1];
        #pragma unroll
        for (int gl = 0; gl < 2; ++gl) {
          f2 sx = xw[gl][0] * r0.lo;
          sx += xw[gl][1] * r0.hi;
          sx += xw[gl][2] * r1.lo;
          sx += xw[gl][3] * r1.hi;
          xprojS[tt][gb + gl][u] = xd[gl] + sx.x + sx.y;
        }
      }
    }
  }
  __syncthreads();

  // ================= MAIN =================
  if (wv == 0) {
    // -------- wave A: layer-0 recurrence, fully wave-internal --------
    for (int t = 0; t < T; ++t) {
      const float* hb = h0r[(t - 1) & 7];
      f4 hv[16];
      #pragma unroll
      for (int m = 0; m < 4; ++m)
        #pragma unroll
        for (int c = 0; c < 4; ++c)
          hv[4 * m + c] = *(const f4*)(hb + 16 * m + 4 * ((c + m) & 3));
      {  // throttle: both helpers past step t-5 (xproj[t] ready, rings safe)
        const int lim = t - 4;
        long long ff;
        do {
          ff = __hip_atomic_load((const long long*)&cnt[4], __ATOMIC_ACQUIRE,
                                 __HIP_MEMORY_SCOPE_WORKGROUP);
        } while ((int)ff < lim || (int)(ff >> 32) < lim);
      }
      float xc[4];
      #pragma unroll
      for (int g = 0; g < 4; ++g) xc[g] = xprojS[t & 7][g][u];
      f2 P[4][4];
      #pragma unroll
      for (int g = 0; g < 4; ++g)
        #pragma unroll
        for (int m = 0; m < 4; ++m) P[g][m] = (f2){0.f, 0.f};
      #pragma unroll
      for (int m = 0; m < 4; ++m)
        #pragma unroll
        for (int c = 0; c < 4; ++c) {
          const f4 v = hv[4 * m + c];
          #pragma unroll
          for (int g = 0; g < 4; ++g) {
            P[g][m] += wA[g][m][c][0] * v.lo;
            P[g][m] += wA[g][m][c][1] * v.hi;
          }
        }
      float a[4];
      #pragma unroll
      for (int g = 0; g < 4; ++g) {
        float pr[4];
        pr[0] = P[g][0].x + P[g][0].y;
        pr[1] = P[g][1].x + P[g][1].y;
        pr[2] = P[g][2].x + P[g][2].y;
        pr[3] = P[g][3].x + P[g][3].y;
        const float gg =
            ((pr[g] + pr[(g + 1) & 3]) + (pr[(g + 2) & 3] + pr[(g + 3) & 3]));
        const float gv = (gg + b4[g]) + xc[g];
        const float am = (g == 2) ? 2.0f : 1.0f;
        const float ab = (g == 2) ? -1.0f : 0.0f;
        const float e = __expf(-gv * am);
        const float s = __fdividef(1.0f, 1.0f + e);
        a[g] = fmaf(s, am, ab);
      }
      cS = a[1] * cS + a[0] * a[2];
      const float e2 = __expf(-2.0f * cS);
      hS = a[3] * (__fdividef(2.0f, 1.0f + e2) - 1.0f);
      h0r[t & 7][u] = hS;
      if (u == 0)
        __hip_atomic_store(&cnt[0], t + 1, __ATOMIC_RELEASE,
                           __HIP_MEMORY_SCOPE_WORKGROUP);
    }
    outp[T * NF + u]       = hS;
    outp[T * NF + 128 + u] = cS;
  } else if (wv == 1) {
    // -------- wave B: layer-1 recurrence (ih half precomputed) --------
    for (int t = 0; t < T; ++t) {
      const float* hb = h1r[(t - 1) & 3];
      f4 hv[16];
      #pragma unroll
      for (int ls = 0; ls < 2; ++ls)
        #pragma unroll
        for (int c = 0; c < 8; ++c)
          hv[8 * ls + c] = *(const f4*)(hb + 32 * ls + 4 * ((c + 4 + 2 * ls) & 7));
      WAIT_GE(2, 2 * t + 2);   // both helpers released partial[t]
      float pl[4], pH[4];
      #pragma unroll
      for (int g = 0; g < 4; ++g) {
        pl[g] = partS[t & 7][g][0][u];
        pH[g] = partS[t & 7][g][1][u];
      }
      f2 P[4][2];
      #pragma unroll
      for (int g = 0; g < 4; ++g)
        #pragma unroll
        for (int ls = 0; ls < 2; ++ls) P[g][ls] = (f2){0.f, 0.f};
      #pragma unroll
      for (int ls = 0; ls < 2; ++ls)
        #pragma unroll
        for (int c = 0; c < 8; ++c) {
          const f4 v = hv[8 * ls + c];
          #pragma unroll
          for (int g = 0; g < 4; ++g) {
            P[g][ls] += wB[g][ls][c][0] * v.lo;
            P[g][ls] += wB[g][ls][c][1] * v.hi;
          }
        }
      float a[4];
      #pragma unroll
      for (int g = 0; g < 4; ++g) {
        float pr[4];
        pr[0] = pl[g];
        pr[1] = pH[g];
        pr[2] = P[g][0].x + P[g][0].y;
        pr[3] = P[g][1].x + P[g][1].y;
        const float gg =
            ((pr[g] + pr[(g + 1) & 3]) + (pr[(g + 2) & 3] + pr[(g + 3) & 3]));
        const float gv = gg + b4[g];
        const float am = (g == 2) ? 2.0f : 1.0f;
        const float ab = (g == 2) ? -1.0f : 0.0f;
        const float e = __expf(-gv * am);
        const float s = __fdividef(1.0f, 1.0f + e);
        a[g] = fmaf(s, am, ab);
      }
      cS = a[1] * cS + a[0] * a[2];
      const float e2 = __expf(-2.0f * cS);
      hS = a[3] * (__fdividef(2.0f, 1.0f + e2) - 1.0f);
      h1r[t & 3][u] = hS;
      if (u == 0)
        __hip_atomic_store(&cnt[1], t + 1, __ATOMIC_RELEASE,
                           __HIP_MEMORY_SCOPE_WORKGROUP);
    }
    outp[T * NF + 64 + u]  = hS;
    outp[T * NF + 192 + u] = cS;
  } else {
    // -------- helper waves --------
    f4 tr0 = {0.f, 0.f, 0.f, 0.f}, tr1 = {0.f, 0.f, 0.f, 0.f};
    const int tend = T + 3;
    for (int tau = 0; tau <= tend; ++tau) {
      // ---- W_ih1 @ h0[tau] slice partials ----
      if (tau <= T - 1) {
        WAIT_GE(0, tau + 1);   // h0[tau] published
        WAIT_GE(1, tau - 7);   // partS ring (depth 8)
        const float* hb = h0r[tau & 7];
        f4 hv[16];
        #pragma unroll
        for (int ls = 0; ls < 2; ++ls)
          #pragma unroll
          for (int c = 0; c < 8; ++c)
            hv[8 * ls + c] = *(const f4*)(hb + 32 * ls + 4 * ((c + 2 * ls) & 7));
        f2 P[2][2];
        #pragma unroll
        for (int gl = 0; gl < 2; ++gl)
          #pragma unroll
          for (int ls = 0; ls < 2; ++ls) P[gl][ls] = (f2){0.f, 0.f};
        #pragma unroll
        for (int ls = 0; ls < 2; ++ls)
          #pragma unroll
          for (int c = 0; c < 8; ++c) {
            const f4 v = hv[8 * ls + c];
            #pragma unroll
            for (int gl = 0; gl < 2; ++gl) {
              P[gl][ls] += wi[gl][ls][c][0] * v.lo;
              P[gl][ls] += wi[gl][ls][c][1] * v.hi;
            }
          }
        #pragma unroll
        for (int gl = 0; gl < 2; ++gl)
          #pragma unroll
          for (int ls = 0; ls < 2; ++ls)
            partS[tau & 7][gb + gl][ls][u] = P[gl][ls].x + P[gl][ls].y;
        if (u == 0)
          __hip_atomic_fetch_add(&cnt[2], 1, __ATOMIC_RELEASE,
                                 __HIP_MEMORY_SCOPE_WORKGROUP);
      }
      // ---- H1: hid[tau-2] ----
      const int sH = tau - 2;
      if (hx == 0 && sH >= 0 && sH <= T - 1) {
        WAIT_GE(1, sH + 1);                  // h1[sH] published
        if (sH >= 8) { WAIT_GE(5, tau - 5); }  // hidS ring vs H2's out
        if (u < 32) {
          const float* hp = h1r[sH & 3];
          f4 hv2[16];
          #pragma unroll
          for (int m = 0; m < 4; ++m)
            #pragma unroll
            for (int c = 0; c < 4; ++c)
              hv2[4 * m + c] = *(const f4*)(hp + 16 * m + 4 * ((c + m) & 3));
          f2 Q[4];
          #pragma unroll
          for (int m = 0; m < 4; ++m) Q[m] = (f2){0.f, 0.f};
          #pragma unroll
          for (int m = 0; m < 4; ++m)
            #pragma unroll
            for (int c = 0; c < 4; ++c) {
              const f4 v = hv2[4 * m + c];
              Q[m] += wh[m][c][0] * v.lo;
              Q[m] += wh[m][c][1] * v.hi;
            }
          const float q0 = Q[0].x + Q[0].y;
          const float q1 = Q[1].x + Q[1].y;
          const float q2 = Q[2].x + Q[2].y;
          const float q3 = Q[3].x + Q[3].y;
          hidS[sH & 7][u] = ((q0 + q1) + (q2 + q3)) + bh;
        }
      }
      // ---- H2: out[tau-4] ----
      const int sO = tau - 4;
      if (hx == 1 && sO >= 0 && sO <= T - 1) {
        WAIT_GE(4, tau - 1);   // H1 finished step tau-2 => hid[sO] ready
        if (u < 8) {
          const float* hp = hidS[sO & 7];
          f2 Q[4];
          #pragma unroll
          for (int k2 = 0; k2 < 4; ++k2) Q[k2] = (f2){0.f, 0.f};
          #pragma unroll
          for (int k2 = 0; k2 < 4; ++k2)
            #pragma unroll
            for (int c = 0; c < 2; ++c) {
              const f4 v = *(const f4*)(hp + 8 * k2 + 4 * ((c + k2) & 1));
              Q[k2] += wo[k2][c][0] * v.lo;
              Q[k2] += wo[k2][c][1] * v.hi;
            }
          const float q0 = Q[0].x + Q[0].y;
          const float q1 = Q[1].x + Q[1].y;
          const float q2 = Q[2].x + Q[2].y;
          const float q3 = Q[3].x + Q[3].y;
          obuf[(sO & 63) * NF + u] = rintf(((q0 + q1) + (q2 + q3)) + bo);
        }
      }
      // ---- xproj[tau+5] (own gates) ----
      const int sX = tau + 5;
      if (sX <= T - 1) {
        const int rr = tau + 4;  // target row = sX - 1
        const f4* trow = (const f4*)&tb[(rr >> 5) & 1][(rr & 31) * NF];
        const f4 r0 = trow[0], r1 = trow[1];
        #pragma unroll
        for (int gl = 0; gl < 2; ++gl) {
          f2 sx = xw[gl][0] * r0.lo;
          sx += xw[gl][1] * r0.hi;
          sx += xw[gl][2] * r1.lo;
          sx += xw[gl][3] * r1.hi;
          xprojS[sX & 7][gb + gl][u] = xd[gl] + sx.x + sx.y;
        }
      }
      // ---- IO (lanes 32-63): own tbuf refill; H2 also stores obuf ----
      if (u >= 32) {
        const int j  = u - 32;
        const int ph = tau & 31;
        if (ph == 8) {
          const int cl = (tau >> 5) + 1;
          if (cl * 32 < T) {
            tr0 = *(const f4*)&target[cl * 256 + j * 8];
            tr1 = *(const f4*)&target[cl * 256 + j * 8 + 4];
          }
        } else if (ph == 26) {
          const int cl = (tau >> 5) + 1;
          if (cl * 32 < T) {
            *(f4*)&tb[cl & 1][j * 8]     = tr0;
            *(f4*)&tb[cl & 1][j * 8 + 4] = tr1;
          }
        }
        if (hx == 1 && ph == 3 && tau >= 35) {
          #pragma unroll
          for (int ii = 0; ii < 2; ++ii) {
            const int fidx = 2 * j + ii;
            const int s  = (tau - 35) + (fidx >> 1);
            const int c4 = (fidx & 1) * 4;
            *(f4*)&outp[s * NF + c4] = *(const f4*)&obuf[(s & 63) * NF + c4];
          }
        }
      }
      if (u == 0)
        __hip_atomic_store(&cnt[4 + hx], tau + 1, __ATOMIC_RELEASE,
                           __HIP_MEMORY_SCOPE_WORKGROUP);
    }
  }
  __syncthreads();

  // ================= EPILOGUE =================
  {
    int s0 = T - 64;
    if (s0 < 0) s0 = 0;
    for (int idx = tid; idx < (T - s0) * NF; idx += 256) {
      const int s = s0 + (idx >> 3);
      outp[s * NF + (idx & 7)] = obuf[(s & 63) * NF + (idx & 7)];
    }
  }
}

extern "C" void kernel_launch(void* const* d_in, const int* in_sizes, int n_in,
                              void* d_out, int out_size, void* d_ws, size_t ws_size,
                              hipStream_t stream) {
  const float* h0in   = (const float*)d_in[1];
  const float* c0in   = (const float*)d_in[2];
  const float* diffp  = (const float*)d_in[3];
  const float* target = (const float*)d_in[4];
  const float* Wih0   = (const float*)d_in[5];
  const float* Whh0   = (const float*)d_in[6];
  const float* bih0   = (const float*)d_in[7];
  const float* bhh0   = (const float*)d_in[8];
  const float* Wih1   = (const float*)d_in[9];
  const float* Whh1   = (const float*)d_in[10];
  const float* bih1   = (const float*)d_in[11];
  const float* bhh1   = (const float*)d_in[12];
  const float* Whid   = (const float*)d_in[13];
  const float* bhidp  = (const float*)d_in[14];
  const float* Woutp  = (const float*)d_in[15];
  const float* boutp  = (const float*)d_in[16];
  float* outp = (float*)d_out;
  const int T = in_sizes[4] / NF;

  decoder_p9<<<dim3(1), dim3(256), 0, stream>>>(
      h0in, c0in, diffp, target,
      Wih0, Whh0, bih0, bhh0,
      Wih1, Whh1, bih1, bhh1,
      Whid, bhidp, Woutp, boutp,
      outp, T);
}

// Round 3
// 10581.752 us; speedup vs baseline: 9.7824x; 9.7824x over previous
//
#include <hip/hip_runtime.h>

#define NF 8
#define RD 256
#define RMASK 255

typedef float f2 __attribute__((ext_vector_type(2)));
typedef float f4 __attribute__((ext_vector_type(4)));

template <int CTRL>
__device__ __forceinline__ float qp(float x) {
  return __int_as_float(
      __builtin_amdgcn_update_dpp(0, __float_as_int(x), CTRL, 0xF, 0xF, true));
}

// Raw barrier: LDS-ordering only (no vmcnt drain -> publisher/loader global
// ops stay in flight across phases).
__device__ __forceinline__ void wg_barrier() {
  asm volatile("s_waitcnt lgkmcnt(0)" ::: "memory");
  __builtin_amdgcn_s_barrier();
  __builtin_amdgcn_sched_barrier(0);
}

// R10: split the two-layer pipeline across TWO CUs (2 blocks x 384 thr).
//  Block0 = L0: waves 0-3 cell (R7 quad-split verbatim), wave4 publisher
//  (h0[t] -> global ring in d_ws, release-flag every 4 steps), wave5 tbuf.
//  Block1 = L1: waves 0-3 cell (R7 verbatim; reads h0 from LDS ring filled
//  by wave4 loader, prefetched 6-8 steps ahead), wave5 head (hid/out/obuf/
//  outp stores, all wave-internal).
//  Sync: raw s_barrier per block (cheap, no vmcnt drain); cross-block via
//  agent-scope acquire/release atomics (XCD-safe). L1 lags L0 by ~8 steps
//  so cross-CU latency is pipelined away. 90KB LDS pad forces 1 block/CU.
//  All arithmetic (rotations, f2 chains, DPP trees, exp chains) is copied
//  verbatim from the validated R7 kernel -> bit-identical results.
__global__ __launch_bounds__(384, 2) void decoder_p10(
    const float* __restrict__ h0in, const float* __restrict__ c0in,
    const float* __restrict__ diffp, const float* __restrict__ target,
    const float* __restrict__ Wih0, const float* __restrict__ Whh0,
    const float* __restrict__ bih0, const float* __restrict__ bhh0,
    const float* __restrict__ Wih1, const float* __restrict__ Whh1,
    const float* __restrict__ bih1, const float* __restrict__ bhh1,
    const float* __restrict__ Whid, const float* __restrict__ bhidp,
    const float* __restrict__ Woutp, const float* __restrict__ boutp,
    float* __restrict__ outp, float* __restrict__ ws, const int T)
{
  const int tid = threadIdx.x;
  const int wv  = tid >> 6;
  const int l   = tid & 63;
  const int q   = l >> 2;
  const int k   = l & 3;
  const int u   = 16 * (wv & 3) + q;
  const int r   = 64 * k + u;
  const bool isk0 = (k == 0);
  const float am = (k == 2) ? 2.0f : 1.0f;
  const float ab = (k == 2) ? -1.0f : 0.0f;

  __shared__ alignas(256) float h0r[4][64];       // block0: h0 ring
  __shared__ alignas(256) float tbuf[2][32 * NF]; // block0: target staging
  __shared__ alignas(256) float h0loc[8][64];     // block1: h0 LDS ring
  __shared__ alignas(256) float h1r[4][64];       // block1: h1 ring
  __shared__ alignas(256) float hidS[4][32];      // block1: hid ring
  __shared__ alignas(256) float obuf[64 * NF];    // block1: out ring
  __shared__ float ldspad[23040];                 // 90KB: force 1 block/CU

  if (T < 0) {  // never true; keeps ldspad allocated
    ldspad[tid] = h0in[tid];
    __syncthreads();
    outp[0] = ldspad[383 - tid];
  }

  int* flag = (int*)ws;          // steps published by block0 (monotone)
  int* cons = (int*)ws + 16;     // block1 loader progress (backpressure)
  float* ring = ws + 64;         // h0 stream ring [RD][64]

  if (blockIdx.x == 0) {
    // ================= BLOCK 0 : layer 0 =================
    f2 wreg[36];
    float b_ = 0.f, xd = 0.f, cS = 0.f, hS = 0.f, xc = 0.f;
    if (wv < 4) {
      #pragma unroll
      for (int j = 0; j < 4; ++j) {
        const int row = 64 * ((k + j) & 3) + u;
        const float* rp = Whh0 + row * 64 + 16 * k;
        #pragma unroll
        for (int c = 0; c < 4; ++c) {
          f4 v = *(const f4*)(rp + 4 * ((c + k) & 3));
          wreg[8 * j + 2 * c]     = v.lo;
          wreg[8 * j + 2 * c + 1] = v.hi;
        }
      }
      b_ = bih0[r] + bhh0[r];
      const float* ra = Wih0 + r * 14;
      #pragma unroll
      for (int c = 0; c < 4; ++c) wreg[32 + c] = (f2){ra[2 * c], ra[2 * c + 1]};
      #pragma unroll
      for (int m = 0; m < 6; ++m) xd += ra[8 + m] * diffp[m];
      if (isk0) cS = c0in[u];
      if (wv == 0) h0r[3][l] = h0in[l];
    } else if (wv == 5) {
      if (l < T) {  // seed tbuf rows 0..63 (both buffers)
        *(f4*)&((float*)tbuf)[l * 8]     = *(const f4*)&target[l * 8];
        *(f4*)&((float*)tbuf)[l * 8 + 4] = *(const f4*)&target[l * 8 + 4];
      }
    }
    __syncthreads();

    int consL = 0;
    f4 tr0 = {0.f, 0.f, 0.f, 0.f}, tr1 = {0.f, 0.f, 0.f, 0.f};
    for (int t = 0; t <= T; ++t) {
      if (wv < 4) {
        if (t < T) {
          const float* base = &h0r[(t - 1) & 3][16 * k];
          f2 P0 = {0.f,0.f}, P1 = {0.f,0.f}, P2 = {0.f,0.f}, P3 = {0.f,0.f};
          #pragma unroll
          for (int c = 0; c < 4; ++c) {
            f4 v = *(const f4*)(base + 4 * ((c + k) & 3));
            P0 += wreg[2*c] * v.lo;      P0 += wreg[2*c+1] * v.hi;
            P1 += wreg[8+2*c] * v.lo;    P1 += wreg[8+2*c+1] * v.hi;
            P2 += wreg[16+2*c] * v.lo;   P2 += wreg[16+2*c+1] * v.hi;
            P3 += wreg[24+2*c] * v.lo;   P3 += wreg[24+2*c+1] * v.hi;
          }
          float p0 = P0.x + P0.y, p1 = P1.x + P1.y;
          float p2 = P2.x + P2.y, p3 = P3.x + P3.y;
          float g = ((p0 + qp<0x39>(p3)) + (qp<0x4E>(p2) + qp<0x93>(p1))) + b_ + xc;
          float e = __expf(-g * am);
          float s = __fdividef(1.0f, 1.0f + e);
          float a = fmaf(s, am, ab);
          float A1 = qp<0xB1>(a), A2 = qp<0x4E>(a), A3 = qp<0x1B>(a);
          if (isk0) {
            cS = A1 * cS + a * A2;
            float e2 = __expf(-2.0f * cS);
            hS = A3 * (__fdividef(2.0f, 1.0f + e2) - 1.0f);
            h0r[t & 3][u] = hS;
          }
        }
        if (t < T - 1) {
          const f4* trow = (const f4*)&tbuf[(t >> 5) & 1][(t & 31) * NF];
          f4 r0 = trow[0], r1 = trow[1];
          f2 s2 = wreg[32] * r0.lo; s2 += wreg[33] * r0.hi;
          s2 += wreg[34] * r1.lo;   s2 += wreg[35] * r1.hi;
          xc = xd + s2.x + s2.y;
        } else xc = 0.f;
      } else if (wv == 4) {
        // -------- publisher --------
        if (t >= 1) {
          if ((t & 3) == 0 && t >= 4 && l == 0)
            __hip_atomic_store(flag, t - 2, __ATOMIC_RELEASE,
                               __HIP_MEMORY_SCOPE_AGENT);
          if ((t & 63) == 0) {
            while (t - consL > RD - 64)
              consL = __hip_atomic_load(cons, __ATOMIC_RELAXED,
                                        __HIP_MEMORY_SCOPE_AGENT);
          }
          ring[((t - 1) & RMASK) * 64 + l] = h0r[(t - 1) & 3][l];
        }
      } else {
        // -------- tbuf refill (split issue/write) --------
        const int ph = t & 31;
        const int cl = (t >> 5) + 1;
        if (l < 32 && cl * 32 < T) {
          if (ph == 8) {
            tr0 = *(const f4*)&target[cl * 256 + l * 8];
            tr1 = *(const f4*)&target[cl * 256 + l * 8 + 4];
          } else if (ph == 26) {
            *(f4*)&tbuf[cl & 1][l * 8]     = tr0;
            *(f4*)&tbuf[cl & 1][l * 8 + 4] = tr1;
          }
        }
      }
      wg_barrier();
    }
    if (wv == 4 && l == 0)
      __hip_atomic_store(flag, T, __ATOMIC_RELEASE, __HIP_MEMORY_SCOPE_AGENT);
    if (wv < 4 && isk0) {
      outp[T * NF + u]       = hS;   // h_final layer 0
      outp[T * NF + 128 + u] = cS;   // c_final layer 0
    }
  } else {
    // ================= BLOCK 1 : layer 1 + heads =================
    f2 wreg[64];
    f2 wH[16], wO[4];
    float b_ = 0.f, cS = 0.f, hS = 0.f;
    float bhA = 0.f, bhB = 0.f, bo_ = 0.f;
    if (wv < 4) {
      const float* Wsrc = (k < 2) ? Wih1 : Whh1;
      const int co = 32 * (k & 1);
      #pragma unroll
      for (int j = 0; j < 4; ++j) {
        const int row = 64 * ((k + j) & 3) + u;
        const float* rp = Wsrc + row * 64 + co;
        #pragma unroll
        for (int c = 0; c < 8; ++c) {
          f4 v = *(const f4*)(rp + 4 * ((c + 2 * k) & 7));
          wreg[16 * j + 2 * c]     = v.lo;
          wreg[16 * j + 2 * c + 1] = v.hi;
        }
      }
      b_ = bih1[r] + bhh1[r];
      if (isk0) cS = c0in[64 + u];
      if (wv == 0) h1r[3][l] = h0in[64 + l];
    } else if (wv == 5) {
      // head: R7-wv0 hid layout + R7-wv1 out layout
      #pragma unroll
      for (int i = 0; i < 2; ++i) {
        const float* rp = Whid + (2 * q + i) * 64 + 16 * k;
        #pragma unroll
        for (int c = 0; c < 4; ++c) {
          f4 v = *(const f4*)(rp + 4 * ((c + k) & 3));
          wH[8 * i + 2 * c]     = v.lo;
          wH[8 * i + 2 * c + 1] = v.hi;
        }
      }
      bhA = bhidp[2 * q];
      bhB = bhidp[2 * q + 1];
      if (q < 8) {
        const float* rp = Woutp + q * 32 + 8 * k;
        #pragma unroll
        for (int c = 0; c < 2; ++c) {
          f4 v = *(const f4*)(rp + 4 * ((c + k) & 1));
          wO[2 * c]     = v.lo;
          wO[2 * c + 1] = v.hi;
        }
        bo_ = boutp[q];
      }
    }
    // loader state
    int flagL = 0, fillW = 0, nPend = 0;
    float b0 = 0.f, b1 = 0.f, b2 = 0.f, b3 = 0.f;
    if (wv == 4) {
      const int pre = (T < 4) ? T : 4;
      while (flagL < pre)
        flagL = __hip_atomic_load(flag, __ATOMIC_ACQUIRE,
                                  __HIP_MEMORY_SCOPE_AGENT);
      for (int s = 0; s < pre; ++s) {
        float v = ring[(s & RMASK) * 64 + l];
        h0loc[s & 7][l] = v;
      }
      fillW = pre;
    }
    __syncthreads();

    const int pend = T + 3;
    for (int p = 0; p <= pend; ++p) {
      if (wv < 4) {
        // -------- L1 cell: h1[p] = cell(h0[p], h1[p-1]) --------
        if (p < T) {
          const float* base = (k < 2) ? &h0loc[p & 7][32 * (k & 1)]
                                      : &h1r[(p - 1) & 3][32 * (k & 1)];
          f2 P0 = {0.f,0.f}, P1 = {0.f,0.f}, P2 = {0.f,0.f}, P3 = {0.f,0.f};
          #pragma unroll
          for (int c = 0; c < 8; ++c) {
            f4 v = *(const f4*)(base + 4 * ((c + 2 * k) & 7));
            P0 += wreg[2*c] * v.lo;      P0 += wreg[2*c+1] * v.hi;
            P1 += wreg[16+2*c] * v.lo;   P1 += wreg[16+2*c+1] * v.hi;
            P2 += wreg[32+2*c] * v.lo;   P2 += wreg[32+2*c+1] * v.hi;
            P3 += wreg[48+2*c] * v.lo;   P3 += wreg[48+2*c+1] * v.hi;
          }
          float p0 = P0.x + P0.y, p1 = P1.x + P1.y;
          float p2 = P2.x + P2.y, p3 = P3.x + P3.y;
          float g = ((p0 + qp<0x39>(p3)) + (qp<0x4E>(p2) + qp<0x93>(p1))) + b_;
          float e = __expf(-g * am);
          float s = __fdividef(1.0f, 1.0f + e);
          float a = fmaf(s, am, ab);
          float A1 = qp<0xB1>(a), A2 = qp<0x4E>(a), A3 = qp<0x1B>(a);
          if (isk0) {
            cS = A1 * cS + a * A2;
            float e2 = __expf(-2.0f * cS);
            hS = A3 * (__fdividef(2.0f, 1.0f + e2) - 1.0f);
            h1r[p & 3][u] = hS;
          }
        }
      } else if (wv == 4) {
        // -------- loader: keep h0loc >= p+2 filled, prefetch to p+8 --------
        if (nPend > 0) h0loc[(fillW + 0) & 7][l] = b0;
        if (nPend > 1) h0loc[(fillW + 1) & 7][l] = b1;
        if (nPend > 2) h0loc[(fillW + 2) & 7][l] = b2;
        if (nPend > 3) h0loc[(fillW + 3) & 7][l] = b3;
        fillW += nPend;
        nPend = 0;
        if ((p & 3) == 0)
          flagL = __hip_atomic_load(flag, __ATOMIC_ACQUIRE,
                                    __HIP_MEMORY_SCOPE_AGENT);
        int need = p + 2; if (need > T) need = T;
        while (fillW < need) {   // emergency (starved): load+write in-phase
          while (flagL < fillW + 1)
            flagL = __hip_atomic_load(flag, __ATOMIC_ACQUIRE,
                                      __HIP_MEMORY_SCOPE_AGENT);
          float v = ring[(fillW & RMASK) * 64 + l];
          h0loc[fillW & 7][l] = v;
          ++fillW;
        }
        int want = flagL;
        if (want > p + 8) want = p + 8;
        if (want > T) want = T;
        int n = want - fillW;
        if (n < 0) n = 0;
        if (n > 4) n = 4;
        if (n > 0) b0 = ring[((fillW + 0) & RMASK) * 64 + l];
        if (n > 1) b1 = ring[((fillW + 1) & RMASK) * 64 + l];
        if (n > 2) b2 = ring[((fillW + 2) & RMASK) * 64 + l];
        if (n > 3) b3 = ring[((fillW + 3) & RMASK) * 64 + l];
        nPend = n;
        if ((p & 63) == 0 && l == 0)
          __hip_atomic_store(cons, p, __ATOMIC_RELAXED,
                             __HIP_MEMORY_SCOPE_AGENT);
      } else {
        // -------- head: hid[p-2], out[p-4], stores --------
        const int sH = p - 2;
        if (sH >= 0 && sH < T) {
          const float* hp = &h1r[sH & 3][16 * k];
          f2 pa = {0.f,0.f}, pb = {0.f,0.f};
          #pragma unroll
          for (int c = 0; c < 4; ++c) {
            f4 v = *(const f4*)(hp + 4 * ((c + k) & 3));
            pa += wH[2*c] * v.lo;     pa += wH[2*c+1] * v.hi;
            pb += wH[8+2*c] * v.lo;   pb += wH[8+2*c+1] * v.hi;
          }
          float sa = pa.x + pa.y; sa += qp<0xB1>(sa); sa += qp<0x4E>(sa);
          float sb = pb.x + pb.y; sb += qp<0xB1>(sb); sb += qp<0x4E>(sb);
          if (isk0) *(f2*)&hidS[sH & 3][2 * q] = (f2){sa + bhA, sb + bhB};
        }
        const int sO = p - 4;
        if (sO >= 0 && sO < T && q < 8) {
          const float* hp = &hidS[sO & 3][8 * k];
          f2 po = {0.f,0.f};
          #pragma unroll
          for (int c = 0; c < 2; ++c) {
            f4 v = *(const f4*)(hp + 4 * ((c + k) & 1));
            po += wO[2*c] * v.lo; po += wO[2*c+1] * v.hi;
          }
          float so = po.x + po.y; so += qp<0xB1>(so); so += qp<0x4E>(so);
          if (isk0) obuf[(sO & 63) * NF + q] = rintf(so + bo_);
        }
        if (l >= 32 && (p & 31) == 5 && p >= 37) {
          const int j = l - 32;
          #pragma unroll
          for (int ii = 0; ii < 2; ++ii) {
            const int fidx = 2 * j + ii;
            const int s  = (p - 37) + (fidx >> 1);
            const int c4 = (fidx & 1) * 4;
            *(f4*)&outp[s * NF + c4] = *(const f4*)&obuf[(s & 63) * NF + c4];
          }
        }
      }
      wg_barrier();
    }
    if (wv < 4 && isk0) {
      outp[T * NF + 64 + u]  = hS;   // h_final layer 1
      outp[T * NF + 192 + u] = cS;   // c_final layer 1
    }
    __syncthreads();
    {
      int s0 = T - 64;
      if (s0 < 0) s0 = 0;
      for (int idx = tid; idx < (T - s0) * NF; idx += 384) {
        const int s = s0 + (idx >> 3);
        outp[s * NF + (idx & 7)] = obuf[(s & 63) * NF + (idx & 7)];
      }
    }
  }
}

extern "C" void kernel_launch(void* const* d_in, const int* in_sizes, int n_in,
                              void* d_out, int out_size, void* d_ws, size_t ws_size,
                              hipStream_t stream) {
  const float* h0in   = (const float*)d_in[1];
  const float* c0in   = (const float*)d_in[2];
  const float* diffp  = (const float*)d_in[3];
  const float* target = (const float*)d_in[4];
  const float* Wih0   = (const float*)d_in[5];
  const float* Whh0   = (const float*)d_in[6];
  const float* bih0   = (const float*)d_in[7];
  const float* bhh0   = (const float*)d_in[8];
  const float* Wih1   = (const float*)d_in[9];
  const float* Whh1   = (const float*)d_in[10];
  const float* bih1   = (const float*)d_in[11];
  const float* bhh1   = (const float*)d_in[12];
  const float* Whid   = (const float*)d_in[13];
  const float* bhidp  = (const float*)d_in[14];
  const float* Woutp  = (const float*)d_in[15];
  const float* boutp  = (const float*)d_in[16];
  float* outp = (float*)d_out;
  const int T = in_sizes[4] / NF;

  hipMemsetAsync(d_ws, 0, 256, stream);   // zero flag+cons (graph-capturable)
  decoder_p10<<<dim3(2), dim3(384), 0, stream>>>(
      h0in, c0in, diffp, target,
      Wih0, Whh0, bih0, bhh0,
      Wih1, Whh1, bih1, bhh1,
      Whid, bhidp, Woutp, boutp,
      outp, (float*)d_ws, T);
}